// Round 4
// baseline (678.974 us; speedup 1.0000x reference)
//
#include <hip/hip_runtime.h>

#define NB 256
#define NT 512
#define NK 128
#define GRP 8

// tie-aware running argmax update: strict > with ascending i => first max wins.
__device__ __forceinline__ void upd(float v, int i, float& bv, int& bi) {
    bool g = v > bv;
    bv = g ? v : bv;
    bi = g ? i : bi;
}

__global__ __launch_bounds__(128, 1)
void crf_decode_kernel(const float* __restrict__ em,
                       const int* __restrict__ mask,
                       const float* __restrict__ trans,
                       int* __restrict__ out) {
    __shared__ alignas(16) float state_sh[2][NK];   // double-buffered Viterbi state
    __shared__ float e_sh[2][GRP][NK];              // prefetched emissions (thread-private slots)
    __shared__ unsigned char bp_sh[(NT - 1) * NK];  // 65408 B backpointers
    __shared__ int tags_sh[NT];
    __shared__ float red_v[2];
    __shared__ int   red_i[2];
    __shared__ int len_sh, lt_sh;

    const int b = blockIdx.x;
    const int j = threadIdx.x;              // 0..127: output tag owned by this thread
    const long base = (long)b * NT * NK;

    // ---- issue first emission group loads (t = 1..GRP) ASAP ----
    float ld[GRP];
    #pragma unroll
    for (int k = 0; k < GRP; ++k) ld[k] = em[base + (1 + k) * NK + j];

    // ---- sequence length = sum(mask[b,:]) ----
    int s = 0;
    #pragma unroll
    for (int k = 0; k < 4; ++k) s += mask[b * NT + j + 128 * k];
    #pragma unroll
    for (int off = 32; off > 0; off >>= 1) s += __shfl_down(s, off, 64);
    if (j == 0) len_sh = 0;
    __syncthreads();
    if ((j & 63) == 0) atomicAdd(&len_sh, s);

    // ---- full transition column j in registers (static indexing only) ----
    float treg[NK];
    #pragma unroll
    for (int i = 0; i < NK; ++i) treg[i] = trans[i * NK + j];

    // ---- init state = emissions[b,0,:] ----
    state_sh[0][j] = em[base + j];
    __syncthreads();
    const int len = len_sh;

    // ---- forward Viterbi: one barrier per step, e prefetched GRP ahead ----
    int cur = 0, cb = 0;
    for (int t0 = 1; t0 < len; t0 += GRP) {
        // park this group's emissions in thread-private LDS slots (waits vmcnt)
        #pragma unroll
        for (int k = 0; k < GRP; ++k) e_sh[cb][k][j] = ld[k];
        // issue next group's loads (land during the ~8 steps below)
        #pragma unroll
        for (int k = 0; k < GRP; ++k) {
            int tt = t0 + GRP + k; tt = tt < NT ? tt : NT - 1;
            ld[k] = em[base + tt * NK + j];
        }
        const int te = (t0 + GRP < len) ? t0 + GRP : len;
        for (int t = t0; t < te; ++t) {
            const float4* sp = (const float4*)state_sh[cur];
            float bv0 = -3.4e38f, bv1 = -3.4e38f, bv2 = -3.4e38f, bv3 = -3.4e38f;
            int   bi0 = 0, bi1 = 1, bi2 = 2, bi3 = 3;
            #pragma unroll
            for (int g = 0; g < 32; ++g) {
                float4 sv = sp[g];                    // wave-uniform broadcast read
                upd(sv.x + treg[4 * g + 0], 4 * g + 0, bv0, bi0);
                upd(sv.y + treg[4 * g + 1], 4 * g + 1, bv1, bi1);
                upd(sv.z + treg[4 * g + 2], 4 * g + 2, bv2, bi2);
                upd(sv.w + treg[4 * g + 3], 4 * g + 3, bv3, bi3);
            }
            // tie-aware merges (prefer smaller i)
            bool tk;
            tk = (bv1 > bv0) || (bv1 == bv0 && bi1 < bi0);
            float mv0 = tk ? bv1 : bv0; int mi0 = tk ? bi1 : bi0;
            tk = (bv3 > bv2) || (bv3 == bv2 && bi3 < bi2);
            float mv1 = tk ? bv3 : bv2; int mi1 = tk ? bi3 : bi2;
            tk = (mv1 > mv0) || (mv1 == mv0 && mi1 < mi0);
            float bv = tk ? mv1 : mv0;  int bi = tk ? mi1 : mi0;

            float e = e_sh[cb][t - t0][j];
            state_sh[cur ^ 1][j] = bv + e;
            bp_sh[(t - 1) * NK + j] = (unsigned char)bi;
            __syncthreads();
            cur ^= 1;
        }
        cb ^= 1;
    }

    // ---- last_tag = argmax_j(state) across 128 threads (2 waves, tie-aware) ----
    {
        float v = state_sh[cur][j];
        int  ix = j;
        #pragma unroll
        for (int off = 32; off > 0; off >>= 1) {
            float vo = __shfl_xor(v, off, 64);
            int   io = __shfl_xor(ix, off, 64);
            bool t2 = (vo > v) || (vo == v && io < ix);
            v  = t2 ? vo : v;
            ix = t2 ? io : ix;
        }
        if ((j & 63) == 0) { red_v[j >> 6] = v; red_i[j >> 6] = ix; }
        __syncthreads();
        if (j == 0) {
            float v0 = red_v[0], v1 = red_v[1];
            int   i0 = red_i[0], i1 = red_i[1];
            bool t2 = (v1 > v0) || (v1 == v0 && i1 < i0);
            lt_sh = t2 ? i1 : i0;
        }
    }
    __syncthreads();
    const int last_tag = lt_sh;
    const int lm1 = (len > 0) ? (len - 1) : 0;

    // ---- positions p >= len-1 all carry last_tag ----
    for (int p = j; p < NT; p += 128)
        if (p >= lm1) tags_sh[p] = last_tag;
    __syncthreads();

    // ---- serial backpointer chase through LDS ----
    if (j == 0) {
        int tag = last_tag;
        for (int p = lm1 - 1; p >= 0; --p) {
            tag = (int)bp_sh[p * NK + tag];
            tags_sh[p] = tag;
        }
    }
    __syncthreads();

    // ---- apply mask and write int32 output ----
    for (int p = j; p < NT; p += 128) {
        int mv = mask[b * NT + p];
        out[b * NT + p] = mv ? tags_sh[p] : 0;
    }
}

extern "C" void kernel_launch(void* const* d_in, const int* in_sizes, int n_in,
                              void* d_out, int out_size, void* d_ws, size_t ws_size,
                              hipStream_t stream) {
    const float* em    = (const float*)d_in[0];
    const int*   mask  = (const int*)d_in[1];
    const float* trans = (const float*)d_in[2];
    int* out = (int*)d_out;
    hipLaunchKernelGGL(crf_decode_kernel, dim3(NB), dim3(128), 0, stream,
                       em, mask, trans, out);
}

// Round 6
// 379.044 us; speedup vs baseline: 1.7913x; 1.7913x over previous
//
#include <hip/hip_runtime.h>

#define NB 256
#define NT 512
#define NK 128
#define GRP 8

// tie-aware running argmax update: strict > with ascending i => first max wins.
__device__ __forceinline__ void upd(float v, int i, float& bv, int& bi) {
    bool g = v > bv;
    bv = g ? v : bv;
    bi = g ? i : bi;
}

__global__ __launch_bounds__(256, 1)
void crf_decode_kernel(const float* __restrict__ em,
                       const int* __restrict__ mask,
                       const float* __restrict__ trans,
                       int* __restrict__ out) {
    __shared__ alignas(16) float state_sh[2][NK];    // double-buffered Viterbi state
    __shared__ unsigned char bp_sh[(NT - 1) * NK];   // 65408 B backpointers
    __shared__ int tags_sh[NT];
    __shared__ int len_sh, lt_sh;

    const int b    = blockIdx.x;
    const int tid  = threadIdx.x;
    const int l    = tid & 63;               // lane
    const int w    = tid >> 6;               // wave 0..3
    const int jj   = (w << 5) | (l & 31);    // output tag owned by this thread
    const int half = l >> 5;                 // i-range half (partner = lane l^32)
    const long base = (long)b * NT * NK;

    // ---- sequence length = sum(mask[b,:]) ----
    int s = mask[b * NT + tid] + mask[b * NT + tid + 256];
    #pragma unroll
    for (int off = 32; off > 0; off >>= 1) s += __shfl_down(s, off, 64);
    if (tid == 0) len_sh = 0;
    __syncthreads();
    if (l == 0) atomicAdd(&len_sh, s);

    // ---- transition column half in registers (64 regs — fits, round 3 proved) ----
    float treg[64];
    #pragma unroll
    for (int ii = 0; ii < 64; ++ii)
        treg[ii] = trans[(half * 64 + ii) * NK + jj];

    // ---- init state = emissions[b,0,:] ----
    if (half == 0) state_sh[0][jj] = em[base + jj];
    __syncthreads();
    const int len = len_sh;

    int cur = 0;
    int t = 1;

    // ---- issue first emission group (t..t+7) ----
    float ld[GRP];
    #pragma unroll
    for (int k = 0; k < GRP; ++k) {
        int tt = t + k; tt = tt < NT ? tt : NT - 1;
        ld[k] = em[base + tt * NK + jj];
    }

    // one Viterbi step; exactly ONE barrier (double-buffered state)
    auto step = [&](int tt, float e) {
        const float4* sp = (const float4*)&state_sh[cur][half * 64];
        float bv0 = -3.4e38f, bv1 = -3.4e38f, bv2 = -3.4e38f, bv3 = -3.4e38f;
        int bi0 = half*64 + 0, bi1 = half*64 + 1, bi2 = half*64 + 2, bi3 = half*64 + 3;
        #pragma unroll
        for (int g = 0; g < 16; ++g) {
            float4 sv = sp[g];                     // 2 distinct addrs/wave: free broadcast
            const int ib = half * 64 + 4 * g;
            upd(sv.x + treg[4*g + 0], ib + 0, bv0, bi0);
            upd(sv.y + treg[4*g + 1], ib + 1, bv1, bi1);
            upd(sv.z + treg[4*g + 2], ib + 2, bv2, bi2);
            upd(sv.w + treg[4*g + 3], ib + 3, bv3, bi3);
        }
        // tie-aware chain merges (prefer smaller i)
        bool tk;
        tk = (bv1 > bv0) || (bv1 == bv0 && bi1 < bi0);
        float mv0 = tk ? bv1 : bv0; int mi0 = tk ? bi1 : bi0;
        tk = (bv3 > bv2) || (bv3 == bv2 && bi3 < bi2);
        float mv1 = tk ? bv3 : bv2; int mi1 = tk ? bi3 : bi2;
        tk = (mv1 > mv0) || (mv1 == mv0 && mi1 < mi0);
        float bv = tk ? mv1 : mv0;  int bi = tk ? mi1 : mi0;

        // cross-half merge via intra-wave shuffle (no LDS, no extra barrier)
        float vo = __shfl_xor(bv, 32, 64);
        int   io = __shfl_xor(bi, 32, 64);
        bool t2 = (vo > bv) || (vo == bv && io < bi);   // lexicographic: first max wins
        float fv = t2 ? vo : bv;
        int   fi = t2 ? io : bi;

        if (half == 0) state_sh[cur ^ 1][jj] = fv + e;          // 32 consecutive floats/wave
        else           bp_sh[(tt - 1) * NK + jj] = (unsigned char)fi;
        __syncthreads();
        cur ^= 1;
    };

    // ---- main loop: groups of 8 steps, emissions prefetched one group ahead ----
    while (t + GRP <= len) {
        float ec[GRP];
        #pragma unroll
        for (int k = 0; k < GRP; ++k) ec[k] = ld[k];
        #pragma unroll
        for (int k = 0; k < GRP; ++k) {
            int tt = t + GRP + k; tt = tt < NT ? tt : NT - 1;
            ld[k] = em[base + tt * NK + jj];
        }
        #pragma unroll
        for (int k = 0; k < GRP; ++k) step(t + k, ec[k]);
        t += GRP;
    }
    for (; t < len; ++t) {                      // tail (<8 steps, exposed loads ok)
        float e = em[base + t * NK + jj];
        step(t, e);
    }

    // ---- last_tag = argmax_j(state) (wave 0, tie-aware) ----
    if (tid < 64) {
        float v0 = state_sh[cur][tid], v1 = state_sh[cur][tid + 64];
        bool take = v1 > v0;                    // tie keeps lower index
        float v = take ? v1 : v0;
        int  ix = take ? tid + 64 : tid;
        #pragma unroll
        for (int off = 32; off > 0; off >>= 1) {
            float vo = __shfl_xor(v, off, 64);
            int   io = __shfl_xor(ix, off, 64);
            bool t2 = (vo > v) || (vo == v && io < ix);
            v  = t2 ? vo : v;
            ix = t2 ? io : ix;
        }
        if (tid == 0) lt_sh = ix;
    }
    __syncthreads();
    const int last_tag = lt_sh;
    const int lm1 = (len > 0) ? (len - 1) : 0;

    // ---- positions p >= len-1 all carry last_tag ----
    for (int p = tid; p < NT; p += 256)
        if (p >= lm1) tags_sh[p] = last_tag;
    __syncthreads();

    // ---- serial backpointer chase through LDS ----
    if (tid == 0) {
        int tag = last_tag;
        for (int p = lm1 - 1; p >= 0; --p) {
            tag = (int)bp_sh[p * NK + tag];
            tags_sh[p] = tag;
        }
    }
    __syncthreads();

    // ---- apply mask and write int32 output ----
    for (int p = tid; p < NT; p += 256) {
        int mv = mask[b * NT + p];
        out[b * NT + p] = mv ? tags_sh[p] : 0;
    }
}

extern "C" void kernel_launch(void* const* d_in, const int* in_sizes, int n_in,
                              void* d_out, int out_size, void* d_ws, size_t ws_size,
                              hipStream_t stream) {
    const float* em    = (const float*)d_in[0];
    const int*   mask  = (const int*)d_in[1];
    const float* trans = (const float*)d_in[2];
    int* out = (int*)d_out;
    hipLaunchKernelGGL(crf_decode_kernel, dim3(NB), dim3(256), 0, stream,
                       em, mask, trans, out);
}

// Round 10
// 335.101 us; speedup vs baseline: 2.0262x; 1.1311x over previous
//
#include <hip/hip_runtime.h>

#define NB 256
#define NT 512
#define NK 128
#define GRP 8

// Hot-loop barrier: drain LDS only (NOT vmcnt) then s_barrier.
// Cross-wave dependencies are exclusively through LDS; emission prefetch
// (global loads) stays in flight across steps. sched_barrier(0) guards
// against compiler hoisting dependent ops above the asm (rule #18).
#define WAVE_BARRIER() do {                                            \
    asm volatile("s_waitcnt lgkmcnt(0)\n\ts_barrier" ::: "memory");    \
    __builtin_amdgcn_sched_barrier(0);                                 \
} while (0)

// tie-aware running argmax update: strict > with ascending i => first max wins.
// max-chain (v_max) and index-chain (v_cndmask) are independent.
__device__ __forceinline__ void upd(float v, int i, float& bv, int& bi) {
    bool g = v > bv;
    bv = fmaxf(v, bv);
    bi = g ? i : bi;
}

__global__ __launch_bounds__(256, 1)
void crf_decode_kernel(const float* __restrict__ em,
                       const int* __restrict__ mask,
                       const float* __restrict__ trans,
                       int* __restrict__ out) {
    __shared__ alignas(16) float state_sh[2][NK];    // double-buffered Viterbi state
    __shared__ alignas(16) unsigned char bp_sh[(NT - 1) * NK];  // backpointers
    __shared__ int tags_sh[NT];
    __shared__ int len_sh, lt_sh;

    const int b    = blockIdx.x;
    const int tid  = threadIdx.x;
    const int l    = tid & 63;               // lane
    const int w    = tid >> 6;               // wave 0..3
    const int jj   = (w << 5) | (l & 31);    // output tag owned by this thread
    const int half = l >> 5;                 // i-range half (partner = lane l^32)
    const long base = (long)b * NT * NK;

    // ---- sequence length = sum(mask[b,:]) ----
    int s = mask[b * NT + tid] + mask[b * NT + tid + 256];
    #pragma unroll
    for (int off = 32; off > 0; off >>= 1) s += __shfl_down(s, off, 64);
    if (tid == 0) len_sh = 0;
    __syncthreads();
    if (l == 0) atomicAdd(&len_sh, s);

    // ---- transition column half in registers ----
    float treg[64];
    #pragma unroll
    for (int ii = 0; ii < 64; ++ii)
        treg[ii] = trans[(half * 64 + ii) * NK + jj];

    // ---- init state = emissions[b,0,:] ----
    if (half == 0) state_sh[0][jj] = em[base + jj];
    __syncthreads();
    const int len = len_sh;

    int cur = 0;
    int t = 1;

    // ---- issue first emission group (t..t+7) ----
    float ld[GRP];
    #pragma unroll
    for (int k = 0; k < GRP; ++k) {
        int tt = t + k; tt = tt < NT ? tt : NT - 1;
        ld[k] = em[base + tt * NK + jj];
    }

    // one Viterbi step; ONE lgkm-only barrier (double-buffered state)
    auto step = [&](int tt, float e) {
        const float4* sp = (const float4*)&state_sh[cur][half * 64];
        float bv0 = -3.4e38f, bv1 = -3.4e38f, bv2 = -3.4e38f, bv3 = -3.4e38f;
        int bi0 = half*64 + 0, bi1 = half*64 + 1, bi2 = half*64 + 2, bi3 = half*64 + 3;
        #pragma unroll
        for (int g = 0; g < 16; ++g) {
            float4 sv = sp[g];                     // broadcast ds_read_b128
            const int ib = half * 64 + 4 * g;
            upd(sv.x + treg[4*g + 0], ib + 0, bv0, bi0);
            upd(sv.y + treg[4*g + 1], ib + 1, bv1, bi1);
            upd(sv.z + treg[4*g + 2], ib + 2, bv2, bi2);
            upd(sv.w + treg[4*g + 3], ib + 3, bv3, bi3);
        }
        // tie-aware chain merges (prefer smaller i)
        bool tk;
        tk = (bv1 > bv0) || (bv1 == bv0 && bi1 < bi0);
        float mv0 = tk ? bv1 : bv0; int mi0 = tk ? bi1 : bi0;
        tk = (bv3 > bv2) || (bv3 == bv2 && bi3 < bi2);
        float mv1 = tk ? bv3 : bv2; int mi1 = tk ? bi3 : bi2;
        tk = (mv1 > mv0) || (mv1 == mv0 && mi1 < mi0);
        float bv = tk ? mv1 : mv0;  int bi = tk ? mi1 : mi0;

        // cross-half merge via intra-wave shuffle (PROVEN in round 6)
        float vo = __shfl_xor(bv, 32, 64);
        int   io = __shfl_xor(bi, 32, 64);
        bool t2 = (vo > bv) || (vo == bv && io < bi);   // lexicographic: first max wins
        float fv = t2 ? vo : bv;
        int   fi = t2 ? io : bi;

        if (half == 0) state_sh[cur ^ 1][jj] = fv + e;
        else           bp_sh[(tt - 1) * NK + jj] = (unsigned char)fi;
        WAVE_BARRIER();
        cur ^= 1;
    };

    // ---- main loop: groups of 8 steps, emissions prefetched one group ahead ----
    while (t + GRP <= len) {
        float ec[GRP];
        #pragma unroll
        for (int k = 0; k < GRP; ++k) ec[k] = ld[k];
        #pragma unroll
        for (int k = 0; k < GRP; ++k) {
            int tt = t + GRP + k; tt = tt < NT ? tt : NT - 1;
            ld[k] = em[base + tt * NK + jj];
        }
        #pragma unroll
        for (int k = 0; k < GRP; ++k) step(t + k, ec[k]);
        t += GRP;
    }
    for (; t < len; ++t) {                      // tail (<8 steps)
        float e = em[base + t * NK + jj];
        step(t, e);
    }

    // ---- last_tag = argmax_j(state) (wave 0, tie-aware) ----
    if (tid < 64) {
        float v0 = state_sh[cur][tid], v1 = state_sh[cur][tid + 64];
        bool take = v1 > v0;                    // tie keeps lower index
        float v = take ? v1 : v0;
        int  ix = take ? tid + 64 : tid;
        #pragma unroll
        for (int off = 32; off > 0; off >>= 1) {
            float vo = __shfl_xor(v, off, 64);
            int   io = __shfl_xor(ix, off, 64);
            bool t2 = (vo > v) || (vo == v && io < ix);
            v  = t2 ? vo : v;
            ix = t2 ? io : ix;
        }
        if (tid == 0) lt_sh = ix;
    }
    __syncthreads();
    const int last_tag = lt_sh;
    const int lm1 = (len > 0) ? (len - 1) : 0;

    // ---- positions p >= len-1 all carry last_tag ----
    for (int p = tid; p < NT; p += 256)
        if (p >= lm1) tags_sh[p] = last_tag;
    __syncthreads();

    // ---- fast backpointer chase (wave 0): pipelined row reads + readlane hop ----
    // Row p = 128 bytes = 32 words; one VGPR holds 2 rows (lanes 0-31 row a, 32-63 row b).
    if (tid < 64) {
        const unsigned int* bpw = (const unsigned int*)bp_sh;
        int tag = last_tag;
        int p = lm1 - 1;
        // head: slow-chase until remaining row count is a multiple of 8
        while (p >= 0 && ((p + 1) & 7)) {
            tag = (int)bp_sh[p * NK + tag];
            if (l == 0) tags_sh[p] = tag;
            --p;
        }
        if (p >= 7) {
            int cb = p - 7;                       // chunk = rows [cb, cb+8)
            unsigned int cur0, cur1, cur2, cur3;
            cur0 = bpw[(cb + 0 + (l >> 5)) * 32 + (l & 31)];
            cur1 = bpw[(cb + 2 + (l >> 5)) * 32 + (l & 31)];
            cur2 = bpw[(cb + 4 + (l >> 5)) * 32 + (l & 31)];
            cur3 = bpw[(cb + 6 + (l >> 5)) * 32 + (l & 31)];
            while (true) {
                const int nb = cb - 8;
                unsigned int nxt0 = 0, nxt1 = 0, nxt2 = 0, nxt3 = 0;
                if (nb >= 0) {                     // prefetch next chunk (uniform branch)
                    nxt0 = bpw[(nb + 0 + (l >> 5)) * 32 + (l & 31)];
                    nxt1 = bpw[(nb + 2 + (l >> 5)) * 32 + (l & 31)];
                    nxt2 = bpw[(nb + 4 + (l >> 5)) * 32 + (l & 31)];
                    nxt3 = bpw[(nb + 6 + (l >> 5)) * 32 + (l & 31)];
                }
                // chase rows cb+7 .. cb (readlane: ~4cy vs ds_read ~120cy)
                unsigned int wd;
                wd = __builtin_amdgcn_readlane(cur3, 32 + (tag >> 2));
                tag = (int)((wd >> ((tag & 3) * 8)) & 0xFF);
                if (l == 0) tags_sh[cb + 7] = tag;
                wd = __builtin_amdgcn_readlane(cur3, (tag >> 2));
                tag = (int)((wd >> ((tag & 3) * 8)) & 0xFF);
                if (l == 0) tags_sh[cb + 6] = tag;
                wd = __builtin_amdgcn_readlane(cur2, 32 + (tag >> 2));
                tag = (int)((wd >> ((tag & 3) * 8)) & 0xFF);
                if (l == 0) tags_sh[cb + 5] = tag;
                wd = __builtin_amdgcn_readlane(cur2, (tag >> 2));
                tag = (int)((wd >> ((tag & 3) * 8)) & 0xFF);
                if (l == 0) tags_sh[cb + 4] = tag;
                wd = __builtin_amdgcn_readlane(cur1, 32 + (tag >> 2));
                tag = (int)((wd >> ((tag & 3) * 8)) & 0xFF);
                if (l == 0) tags_sh[cb + 3] = tag;
                wd = __builtin_amdgcn_readlane(cur1, (tag >> 2));
                tag = (int)((wd >> ((tag & 3) * 8)) & 0xFF);
                if (l == 0) tags_sh[cb + 2] = tag;
                wd = __builtin_amdgcn_readlane(cur0, 32 + (tag >> 2));
                tag = (int)((wd >> ((tag & 3) * 8)) & 0xFF);
                if (l == 0) tags_sh[cb + 1] = tag;
                wd = __builtin_amdgcn_readlane(cur0, (tag >> 2));
                tag = (int)((wd >> ((tag & 3) * 8)) & 0xFF);
                if (l == 0) tags_sh[cb + 0] = tag;
                if (nb < 0) break;
                cur0 = nxt0; cur1 = nxt1; cur2 = nxt2; cur3 = nxt3;
                cb = nb;
            }
        }
    }
    __syncthreads();

    // ---- apply mask and write int32 output ----
    for (int p = tid; p < NT; p += 256) {
        int mv = mask[b * NT + p];
        out[b * NT + p] = mv ? tags_sh[p] : 0;
    }
}

extern "C" void kernel_launch(void* const* d_in, const int* in_sizes, int n_in,
                              void* d_out, int out_size, void* d_ws, size_t ws_size,
                              hipStream_t stream) {
    const float* em    = (const float*)d_in[0];
    const int*   mask  = (const int*)d_in[1];
    const float* trans = (const float*)d_in[2];
    int* out = (int*)d_out;
    hipLaunchKernelGGL(crf_decode_kernel, dim3(NB), dim3(256), 0, stream,
                       em, mask, trans, out);
}